// Round 10
// baseline (501.709 us; speedup 1.0000x reference)
//
#include <hip/hip_runtime.h>
#include <hip/hip_bf16.h>
#include <math.h>

// Problem constants
#define NB   1024   // batch
#define NT   60     // time steps
#define NC   10     // in channels
#define NDM  256    // d_model
#define NH   16     // heads
#define NDH  16     // per-head value dim
#define NA   13     // num attention queries
#define NM   208    // NA*NH
#define NMO  128    // MLP out

// weff6 row: 128 groups x 32 floats (128 B aligned); group g = d-pair (2g, 2g+1),
// slot dl*13+ak for dl in {0,1}; slots 26..31 pad. Row = 4096 floats.
#define WROW6 4096

// Workspace layout (floats)
#define OFF_WEFF  0
#define N_WEFF    (NH*14*WROW6)                // 917,504
#define OFF_BEFF  (OFF_WEFF + N_WEFF)
#define N_BEFF    (NM*NH*NA)                   // 43,264
#define OFF_VGT   (OFF_BEFF + N_BEFF)
#define N_VGT     (NB*NDM*64)                  // 16,777,216 (v transposed [b][d][64])
#define OFF_ATT   (OFF_VGT + N_VGT)
#define N_ATT     (NM*NB*NDH)                  // 3,407,872

#define LDS_FENCE() __asm__ __volatile__("s_waitcnt lgkmcnt(0)" ::: "memory")

// ---------------- K0: weff6[hk][mi][g][32], m = 13*hk+mi
__global__ void ltae_weff(const float* __restrict__ Q, const float* __restrict__ Wk,
                          const float* __restrict__ bk, float* __restrict__ weff6,
                          float* __restrict__ beff2) {
    int blk = blockIdx.x;            // hk*14 + mi
    int hk = blk / 14, mi = blk - hk*14;
    int m  = hk*13 + mi;
    int mc = m > 207 ? 207 : m;      // slot (15,13) provably never read
    int d = threadIdx.x;
    float q0 = Q[mc*4+0], q1 = Q[mc*4+1], q2 = Q[mc*4+2], q3 = Q[mc*4+3];
    int g = d >> 1, dl = d & 1;
    size_t base = (size_t)blk*WROW6 + g*32 + dl*13;
#pragma unroll
    for (int ak = 0; ak < NA; ++ak) {
        int e = (ak*16 + hk)*4;
        float w = q0*Wk[(size_t)(e+0)*NDM + d] + q1*Wk[(size_t)(e+1)*NDM + d]
                + q2*Wk[(size_t)(e+2)*NDM + d] + q3*Wk[(size_t)(e+3)*NDM + d];
        weff6[base + ak] = w;
    }
    if (dl == 1) {               // zero the 6 pad slots of this group
#pragma unroll
        for (int p = 26; p < 32; ++p) weff6[(size_t)blk*WROW6 + g*32 + p] = 0.f;
    }
    if (d < NA && m <= 207) {
        int e = (d*16 + hk)*4;
        beff2[(m*16 + hk)*NA + d] = q0*bk[e] + q1*bk[e+1] + q2*bk[e+2] + q3*bk[e+3];
    }
}

// ---------------- K1: conv 1x1 + GroupNorm -> vgT[b][d][64] (t-padded, coalesced)
#define VT_S 66
#define K1_LDS_BYTES ((NDM*VT_S + NT*NC)*4)

__launch_bounds__(1024, 8)
__global__ void ltae_convgn(const float* __restrict__ x, const float* __restrict__ Wc,
                            const float* __restrict__ bc, const float* __restrict__ gnw,
                            const float* __restrict__ gnb, float* __restrict__ vgT) {
    extern __shared__ float smem[];
    float* Vt = smem;
    float* xs = smem + NDM*VT_S;
    int b = blockIdx.x, tid = threadIdx.x;
    if (tid < NT*NC) xs[tid] = x[(size_t)b*NT*NC + tid];
    __syncthreads();
    {
        int d = tid >> 2, q = tid & 3;   // wave = 16 d = one GN group
        float wc[NC];
#pragma unroll
        for (int c = 0; c < NC; ++c) wc[c] = Wc[d*NC + c];
        float bcv = bc[d];
        float h[15];
        float s1 = 0.f, s2 = 0.f;
#pragma unroll
        for (int k = 0; k < 15; ++k) {
            int t = 15*q + k;
            float a = bcv;
#pragma unroll
            for (int c = 0; c < NC; ++c) a = fmaf(xs[t*NC + c], wc[c], a);
            h[k] = a; s1 += a; s2 += a*a;
        }
#pragma unroll
        for (int off = 1; off < 64; off <<= 1) {
            s1 += __shfl_xor(s1, off);
            s2 += __shfl_xor(s2, off);
        }
        float mean = s1 * (1.f/960.f);
        float var  = s2 * (1.f/960.f) - mean*mean;
        float rstd = rsqrtf(var + 1e-5f);
        float g = gnw[d], bb = gnb[d];
#pragma unroll
        for (int k = 0; k < 15; ++k)
            Vt[d*VT_S + 15*q + k] = (h[k]-mean)*rstd*g + bb;
    }
    __syncthreads();
    // float4 stores: 4x fewer store instructions than scalar
    float* vb = vgT + (size_t)b*NDM*64;
    for (int i = tid; i < NDM*16; i += 1024) {
        int d = i >> 4, t4 = (i & 15) << 2;
        float4 o;
        o.x = (t4+0 < NT) ? Vt[d*VT_S + t4+0] : 0.f;
        o.y = (t4+1 < NT) ? Vt[d*VT_S + t4+1] : 0.f;
        o.z = (t4+2 < NT) ? Vt[d*VT_S + t4+2] : 0.f;
        o.w = (t4+3 < NT) ? Vt[d*VT_S + t4+3] : 0.f;
        *(float4*)&vb[d*64 + t4] = o;
    }
}

// ---------------- K2: scrambled attention; block = (1 hk) x (4 b-pairs).
// R9 theory (from R7's decisive negative): the dominant serializer is the
// SCALAR weight path — 24 waves/CU streaming up to 24 DISTINCT 16KB rows
// thrash the per-CU scalar cache; every s_load_dwordx16 pair misses to L2
// (~200cy) against only 104 FMA cycles -> VALUBusy 43%. FLIP the mapping:
// the 4 waves of a block now stream the IDENTICAL weight row (same hk,
// near-lockstep) -> 1 miss serves 4 waves; distinct rows per CU 24 -> 6.
// v locality moves block-level -> XCD-level (one bg8's 512KB of v read by
// the 16 hk-blocks on that XCD; 4MB L2 holds it). Per-wave code is
// byte-identical to R2 (proven 28 VGPR / 190us structure).
#define BSTRIDE (NDM*64)
__launch_bounds__(256, 6)
__global__ void ltae_attn(const float* __restrict__ vgT, const float* __restrict__ weff6,
                          const float* __restrict__ beff2, float* __restrict__ attout) {
    __shared__ float wbuf[4*784];        // 12,544 B
    int p = blockIdx.x;                  // 2048 = 8 xcd * 16 bg8 * 16 hk
    int xcd = p & 7, idx = p >> 3;
    int bg8 = xcd * 16 + (idx >> 4);     // bijective: 8*16*16 = 2048
    int hkq = idx & 15;                  // block's head index
    int tid = threadIdx.x;
    int wid = tid >> 6, lane = tid & 63;
    int hk = __builtin_amdgcn_readfirstlane(hkq);        // uniform -> scalar path
    int b0 = bg8*8 + wid*2;              // wave owns b-pair (b0, b0+1)
    int tk = lane;
    int mi0    = (13*b0) >> 10;                          // wave-uniform
    int rstar0 = ((mi0+1) << 10) - 13*b0;                // switch for b0+jb iff rstar0-13jb < 13
    const float* __restrict__ wrow = weff6 + (size_t)(hk*14 + mi0)*WROW6;
    const float* __restrict__ vX   = vgT + (size_t)b0*BSTRIDE + tk;
    float* myC = wbuf + wid*784;

    float acc[2][13];
#pragma unroll
    for (int jb = 0; jb < 2; ++jb)
#pragma unroll
        for (int j = 0; j < 13; ++j) acc[jb][j] = 0.f;

    // ---- pass A: row (hk, mi0), 128 d-pair groups (2 per iteration), shared
    // across 2 b. Loads batched up-front, FMAs after a single wait pair.
#pragma unroll 1
    for (int gg = 0; gg < 64; ++gg) {
        const float* wgA = wrow + (size_t)(2*gg)*32;     // uniform -> s_load
        const float* wgB = wrow + (size_t)(2*gg+1)*32;
        float a0[2], a1[2], c0[2], c1[2];
#pragma unroll
        for (int jb = 0; jb < 2; ++jb) {
            a0[jb] = vX[jb*BSTRIDE + (4*gg+0)*64];
            a1[jb] = vX[jb*BSTRIDE + (4*gg+1)*64];
            c0[jb] = vX[jb*BSTRIDE + (4*gg+2)*64];
            c1[jb] = vX[jb*BSTRIDE + (4*gg+3)*64];
        }
#pragma unroll
        for (int jb = 0; jb < 2; ++jb)
#pragma unroll
            for (int ak = 0; ak < 13; ++ak)
                acc[jb][ak] = fmaf(a1[jb], wgA[13+ak], fmaf(a0[jb], wgA[ak], acc[jb][ak]));
#pragma unroll
        for (int jb = 0; jb < 2; ++jb)
#pragma unroll
            for (int ak = 0; ak < 13; ++ak)
                acc[jb][ak] = fmaf(c1[jb], wgB[13+ak], fmaf(c0[jb], wgB[ak], acc[jb][ak]));
    }

    // ---- pass B per b where needed: row (hk, mi0+1). FULLY UNROLLED so acc
    // indexing stays static (dynamic indexing demotes acc to scratch — R13 bug).
#pragma unroll
    for (int jb = 0; jb < 2; ++jb) {
        int rstar_j = rstar0 - 13*jb;
        if (rstar_j < 13) {
            int ustar = 60*rstar_j;
            int tstar = (ustar >= 1) ? (ustar/13) : -1;
            if (tk == tstar) {
#pragma unroll
                for (int j = 0; j < 13; ++j) myC[j] = acc[jb][j];
            }
            LDS_FENCE();
            if (tk >= tstar) {
#pragma unroll
                for (int j = 0; j < 13; ++j) acc[jb][j] = 0.f;
                const float* __restrict__ wrow2 = weff6 + (size_t)(hk*14 + mi0 + 1)*WROW6;
#pragma unroll 1
                for (int g = 0; g < 128; ++g) {
                    const float* wg = wrow2 + g*32;
                    float v0 = vX[jb*BSTRIDE + (2*g)*64];
                    float v1 = vX[jb*BSTRIDE + (2*g+1)*64];
#pragma unroll
                    for (int ak = 0; ak < 13; ++ak)
                        acc[jb][ak] = fmaf(v1, wg[13+ak], fmaf(v0, wg[ak], acc[jb][ak]));
                }
            }
            if (tk == tstar) {
#pragma unroll
                for (int j = 0; j < 13; ++j)
                    if (13*tk + j < ustar) acc[jb][j] = myC[j];
            }
            LDS_FENCE();
        }
    }

    // ---- softmax + AV per b; FULLY UNROLLED jb (static acc indexing)
    int dh = lane >> 2, cc = lane & 3;
#pragma unroll
    for (int jb = 0; jb < 2; ++jb) {
        int b = b0 + jb;
        int hb13 = (hk*1024 + b)*13;
        if (tk < NT) {
#pragma unroll
            for (int j = 0; j < 13; ++j) myC[13*tk + j] = acc[jb][j];
        }
        LDS_FENCE();
        float vreg[15];
#pragma unroll
        for (int j = 0; j < 15; ++j)
            vreg[j] = vgT[((size_t)b*NDM + hk*16 + dh)*64 + cc + 4*j];
#pragma unroll 1
        for (int r = 0; r < 13; ++r) {
            int n = hb13 + r;
            int m = n >> 10;                         // exact variant for this row
            int brow = (m*16 + hk)*13;
            float logit = -1e30f;
            if (lane < NT) {
                int u  = r*60 + lane;
                int ak = u % 13;
                logit = (myC[u] + beff2[brow + ak]) * 0.5f;
            }
            float mx = logit;
#pragma unroll
            for (int off = 32; off; off >>= 1) mx = fmaxf(mx, __shfl_xor(mx, off));
            float e = (lane < NT) ? __expf(logit - mx) : 0.f;
            float s = e;
#pragma unroll
            for (int off = 32; off; off >>= 1) s += __shfl_xor(s, off);
            float attn = e / s;
            if (lane < NT) myC[r*60 + lane] = attn;  // same-wave in-order LDS
            LDS_FENCE();
            float a = 0.f;
#pragma unroll
            for (int j = 0; j < 15; ++j)
                a = fmaf(myC[r*60 + cc + 4*j], vreg[j], a);
            a += __shfl_xor(a, 1);
            a += __shfl_xor(a, 2);
            if (cc == 0) attout[(size_t)n*NDH + dh] = a;
        }
        LDS_FENCE();
    }
}

// ---------------- K3: MLP + BN(eval) + ReLU + GroupNorm(16,128); 16 rows/block.
// R9-verified WIN (~75us): j = tid>>3, sl = tid&7 -> 8 lanes SHARE each W1
// row (float4 wave-load = 2 cachelines, was 64). f stride 260 keeps the 8
// distinct f[sl] reads conflict-free. GN octet at lane stride 8 -> shuffle
// offsets {8,16,32}. Math identical to original.
#define FS 260
__launch_bounds__(1024)
__global__ void ltae_mlp(const float* __restrict__ attout, const float* __restrict__ W1,
                         const float* __restrict__ b1, const float* __restrict__ bnw,
                         const float* __restrict__ bnb, const float* __restrict__ bnrm,
                         const float* __restrict__ bnrv, const float* __restrict__ gow,
                         const float* __restrict__ gob, float* __restrict__ out) {
    __shared__ float f[16*FS];   // 16,640 B
    int tid = threadIdx.x;
    int sl  = tid & 7;           // sample slot 0..7 (8 lanes share a W1 row)
    int j   = tid >> 3;          // output channel 0..127
    int base = blockIdx.x << 4;  // 16 sids per block; sid = a2*1024 + b2
    for (int k = tid; k < 16*NDM; k += 1024) {
        int s = k >> 8, c = k & 255;
        int sid2 = base + s;
        int aa = sid2 >> 10, bb = sid2 & 1023;
        int h2 = c >> 4, dhh = c & 15;
        f[s*FS + c] = attout[((size_t)((aa*16 + h2)*1024 + bb))*NDH + dhh];
    }
    __syncthreads();
    const float* fr0 = f + sl*FS;
    const float* fr1 = f + (sl+8)*FS;
    const float* w   = &W1[(size_t)j*NDM];
    float bj = b1[j];
    float acc0 = bj, acc1 = bj;
    for (int c = 0; c < NDM; c += 4) {
        float4 wv = *(const float4*)&w[c];      // 8 lanes/addr -> 2 lines/wave
        float4 f0 = *(const float4*)&fr0[c];    // 16B-aligned (FS*4 % 16 == 0)
        float4 f1 = *(const float4*)&fr1[c];
        acc0 += wv.x*f0.x + wv.y*f0.y + wv.z*f0.z + wv.w*f0.w;
        acc1 += wv.x*f1.x + wv.y*f1.y + wv.z*f1.z + wv.w*f1.w;
    }
    float rs = rsqrtf(bnrv[j] + 1e-5f);
    float sc = rs * bnw[j];
    float sh = bnb[j] - bnrm[j]*sc;
    float y0 = fmaxf(acc0*sc + sh, 0.f);
    float y1 = fmaxf(acc1*sc + sh, 0.f);
    float a1 = y0, b1s = y0*y0, a2 = y1, b2s = y1*y1;
#pragma unroll
    for (int off = 8; off < 64; off <<= 1) {    // GN octet at lane stride 8
        a1  += __shfl_xor(a1, off);
        b1s += __shfl_xor(b1s, off);
        a2  += __shfl_xor(a2, off);
        b2s += __shfl_xor(b2s, off);
    }
    float gw = gow[j], gb = gob[j];
    {
        float mean = a1 * 0.125f;
        float var  = b1s * 0.125f - mean*mean;
        float o = (y0 - mean) * rsqrtf(var + 1e-5f) * gw + gb;
        int sid = base + sl, aa = sid >> 10, bb = sid & 1023;
        out[((size_t)bb*NA + aa)*NMO + j] = o;
    }
    {
        float mean = a2 * 0.125f;
        float var  = b2s * 0.125f - mean*mean;
        float o = (y1 - mean) * rsqrtf(var + 1e-5f) * gw + gb;
        int sid = base + sl + 8, aa = sid >> 10, bb = sid & 1023;
        out[((size_t)bb*NA + aa)*NMO + j] = o;
    }
}

extern "C" void kernel_launch(void* const* d_in, const int* in_sizes, int n_in,
                              void* d_out, int out_size, void* d_ws, size_t ws_size,
                              hipStream_t stream) {
    const float* x    = (const float*)d_in[0];
    const float* Wc   = (const float*)d_in[1];
    const float* bc   = (const float*)d_in[2];
    const float* gnw  = (const float*)d_in[3];
    const float* gnb  = (const float*)d_in[4];
    const float* Q    = (const float*)d_in[5];
    const float* Wk   = (const float*)d_in[6];
    const float* bk   = (const float*)d_in[7];
    const float* W1   = (const float*)d_in[8];
    const float* b1   = (const float*)d_in[9];
    const float* bnw  = (const float*)d_in[10];
    const float* bnb  = (const float*)d_in[11];
    const float* bnrm = (const float*)d_in[12];
    const float* bnrv = (const float*)d_in[13];
    const float* gow  = (const float*)d_in[14];
    const float* gob  = (const float*)d_in[15];

    float* ws     = (float*)d_ws;
    float* weff6  = ws + OFF_WEFF;
    float* beff2  = ws + OFF_BEFF;
    float* vgT    = ws + OFF_VGT;
    float* attout = ws + OFF_ATT;
    float* outp   = (float*)d_out;

    hipLaunchKernelGGL(ltae_weff, dim3(NH*14), dim3(256), 0, stream, Q, Wk, bk, weff6, beff2);
    hipFuncSetAttribute((const void*)ltae_convgn,
                        hipFuncAttributeMaxDynamicSharedMemorySize, K1_LDS_BYTES);
    hipLaunchKernelGGL(ltae_convgn, dim3(NB), dim3(1024), K1_LDS_BYTES, stream,
                       x, Wc, bc, gnw, gnb, vgT);
    hipLaunchKernelGGL(ltae_attn, dim3(2048), dim3(256), 0, stream,
                       vgT, weff6, beff2, attout);
    hipLaunchKernelGGL(ltae_mlp, dim3(NA*NB/16), dim3(1024), 0, stream,
                       attout, W1, b1, bnw, bnb, bnrm, bnrv, gow, gob, outp);
}

// Round 11
// 328.850 us; speedup vs baseline: 1.5256x; 1.5256x over previous
//
#include <hip/hip_runtime.h>
#include <hip/hip_bf16.h>
#include <math.h>

// Problem constants
#define NB   1024   // batch
#define NT   60     // time steps
#define NC   10     // in channels
#define NDM  256    // d_model
#define NH   16     // heads
#define NDH  16     // per-head value dim
#define NA   13     // num attention queries
#define NM   208    // NA*NH
#define NMO  128    // MLP out

// weff6 row: 128 groups x 32 floats (128 B aligned); group g = d-pair (2g, 2g+1),
// slot dl*13+ak for dl in {0,1}; slots 26..31 pad. Row = 4096 floats.
#define WROW6 4096

// Workspace layout (floats)
#define OFF_WEFF  0
#define N_WEFF    (NH*14*WROW6)                // 917,504
#define OFF_BEFF  (OFF_WEFF + N_WEFF)
#define N_BEFF    (NM*NH*NA)                   // 43,264
#define OFF_VGT   (OFF_BEFF + N_BEFF)
#define N_VGT     (NB*NDM*64)                  // 16,777,216 (v transposed [b][d][64])
#define OFF_ATT   (OFF_VGT + N_VGT)
#define N_ATT     (NM*NB*NDH)                  // 3,407,872

#define LDS_FENCE() __asm__ __volatile__("s_waitcnt lgkmcnt(0)" ::: "memory")

// ---------------- K0: weff6[hk][mi][g][32], m = 13*hk+mi
__global__ void ltae_weff(const float* __restrict__ Q, const float* __restrict__ Wk,
                          const float* __restrict__ bk, float* __restrict__ weff6,
                          float* __restrict__ beff2) {
    int blk = blockIdx.x;            // hk*14 + mi
    int hk = blk / 14, mi = blk - hk*14;
    int m  = hk*13 + mi;
    int mc = m > 207 ? 207 : m;      // slot (15,13) provably never read
    int d = threadIdx.x;
    float q0 = Q[mc*4+0], q1 = Q[mc*4+1], q2 = Q[mc*4+2], q3 = Q[mc*4+3];
    int g = d >> 1, dl = d & 1;
    size_t base = (size_t)blk*WROW6 + g*32 + dl*13;
#pragma unroll
    for (int ak = 0; ak < NA; ++ak) {
        int e = (ak*16 + hk)*4;
        float w = q0*Wk[(size_t)(e+0)*NDM + d] + q1*Wk[(size_t)(e+1)*NDM + d]
                + q2*Wk[(size_t)(e+2)*NDM + d] + q3*Wk[(size_t)(e+3)*NDM + d];
        weff6[base + ak] = w;
    }
    if (dl == 1) {               // zero the 6 pad slots of this group
#pragma unroll
        for (int p = 26; p < 32; ++p) weff6[(size_t)blk*WROW6 + g*32 + p] = 0.f;
    }
    if (d < NA && m <= 207) {
        int e = (d*16 + hk)*4;
        beff2[(m*16 + hk)*NA + d] = q0*bk[e] + q1*bk[e+1] + q2*bk[e+2] + q3*bk[e+3];
    }
}

// ---------------- K1: conv 1x1 + GroupNorm -> vgT[b][d][64] (t-padded, coalesced)
#define VT_S 66
#define K1_LDS_BYTES ((NDM*VT_S + NT*NC)*4)

__launch_bounds__(1024, 8)
__global__ void ltae_convgn(const float* __restrict__ x, const float* __restrict__ Wc,
                            const float* __restrict__ bc, const float* __restrict__ gnw,
                            const float* __restrict__ gnb, float* __restrict__ vgT) {
    extern __shared__ float smem[];
    float* Vt = smem;
    float* xs = smem + NDM*VT_S;
    int b = blockIdx.x, tid = threadIdx.x;
    if (tid < NT*NC) xs[tid] = x[(size_t)b*NT*NC + tid];
    __syncthreads();
    {
        int d = tid >> 2, q = tid & 3;   // wave = 16 d = one GN group
        float wc[NC];
#pragma unroll
        for (int c = 0; c < NC; ++c) wc[c] = Wc[d*NC + c];
        float bcv = bc[d];
        float h[15];
        float s1 = 0.f, s2 = 0.f;
#pragma unroll
        for (int k = 0; k < 15; ++k) {
            int t = 15*q + k;
            float a = bcv;
#pragma unroll
            for (int c = 0; c < NC; ++c) a = fmaf(xs[t*NC + c], wc[c], a);
            h[k] = a; s1 += a; s2 += a*a;
        }
#pragma unroll
        for (int off = 1; off < 64; off <<= 1) {
            s1 += __shfl_xor(s1, off);
            s2 += __shfl_xor(s2, off);
        }
        float mean = s1 * (1.f/960.f);
        float var  = s2 * (1.f/960.f) - mean*mean;
        float rstd = rsqrtf(var + 1e-5f);
        float g = gnw[d], bb = gnb[d];
#pragma unroll
        for (int k = 0; k < 15; ++k)
            Vt[d*VT_S + 15*q + k] = (h[k]-mean)*rstd*g + bb;
    }
    __syncthreads();
    // float4 stores: 4x fewer store instructions than scalar
    float* vb = vgT + (size_t)b*NDM*64;
    for (int i = tid; i < NDM*16; i += 1024) {
        int d = i >> 4, t4 = (i & 15) << 2;
        float4 o;
        o.x = (t4+0 < NT) ? Vt[d*VT_S + t4+0] : 0.f;
        o.y = (t4+1 < NT) ? Vt[d*VT_S + t4+1] : 0.f;
        o.z = (t4+2 < NT) ? Vt[d*VT_S + t4+2] : 0.f;
        o.w = (t4+3 < NT) ? Vt[d*VT_S + t4+3] : 0.f;
        *(float4*)&vb[d*64 + t4] = o;
    }
}

// ---------------- K2: scrambled attention; block = (1 hk) x (4 b-pairs).
// R10 post-mortem: the weight-sharing mapping was invalidated by a codegen
// regression — b0/mi0 derived from wid WITHOUT readfirstlane -> wrow formally
// divergent -> SGPR 96->32, weights demoted from s_load to per-lane
// global_load (VGPR 40, WRITE 2x, attn 388us). FIX: readfirstlane(b0).
// Now mi0/rstar0/wrow are compiler-provably scalar and the block's 4 waves
// stream the IDENTICAL weight row via the scalar cache in near-lockstep
// (1 miss serves 4 waves; distinct rows/CU 24 -> 6). v locality at XCD
// level (one bg8's 512KB read by that XCD's 16 hk-blocks; 4MB L2 holds it).
// Per-wave code remains byte-identical to R2 (proven 28 VGPR structure).
#define BSTRIDE (NDM*64)
__launch_bounds__(256, 6)
__global__ void ltae_attn(const float* __restrict__ vgT, const float* __restrict__ weff6,
                          const float* __restrict__ beff2, float* __restrict__ attout) {
    __shared__ float wbuf[4*784];        // 12,544 B
    int p = blockIdx.x;                  // 2048 = 8 xcd * 16 bg8 * 16 hk
    int xcd = p & 7, idx = p >> 3;
    int bg8 = xcd * 16 + (idx >> 4);     // bijective: 8*16*16 = 2048
    int hkq = idx & 15;                  // block's head index
    int tid = threadIdx.x;
    int wid = tid >> 6, lane = tid & 63;
    int hk = __builtin_amdgcn_readfirstlane(hkq);        // uniform -> scalar path
    int b0 = __builtin_amdgcn_readfirstlane(bg8*8 + wid*2);  // CRITICAL: scalar b0
    int tk = lane;
    int mi0    = (13*b0) >> 10;                          // now provably scalar
    int rstar0 = ((mi0+1) << 10) - 13*b0;                // switch for b0+jb iff rstar0-13jb < 13
    const float* __restrict__ wrow = weff6 + (size_t)(hk*14 + mi0)*WROW6;
    const float* __restrict__ vX   = vgT + (size_t)b0*BSTRIDE + tk;
    float* myC = wbuf + wid*784;

    float acc[2][13];
#pragma unroll
    for (int jb = 0; jb < 2; ++jb)
#pragma unroll
        for (int j = 0; j < 13; ++j) acc[jb][j] = 0.f;

    // ---- pass A: row (hk, mi0), 128 d-pair groups (2 per iteration), shared
    // across 2 b. Loads batched up-front, FMAs after a single wait pair.
#pragma unroll 1
    for (int gg = 0; gg < 64; ++gg) {
        const float* wgA = wrow + (size_t)(2*gg)*32;     // uniform -> s_load
        const float* wgB = wrow + (size_t)(2*gg+1)*32;
        float a0[2], a1[2], c0[2], c1[2];
#pragma unroll
        for (int jb = 0; jb < 2; ++jb) {
            a0[jb] = vX[jb*BSTRIDE + (4*gg+0)*64];
            a1[jb] = vX[jb*BSTRIDE + (4*gg+1)*64];
            c0[jb] = vX[jb*BSTRIDE + (4*gg+2)*64];
            c1[jb] = vX[jb*BSTRIDE + (4*gg+3)*64];
        }
#pragma unroll
        for (int jb = 0; jb < 2; ++jb)
#pragma unroll
            for (int ak = 0; ak < 13; ++ak)
                acc[jb][ak] = fmaf(a1[jb], wgA[13+ak], fmaf(a0[jb], wgA[ak], acc[jb][ak]));
#pragma unroll
        for (int jb = 0; jb < 2; ++jb)
#pragma unroll
            for (int ak = 0; ak < 13; ++ak)
                acc[jb][ak] = fmaf(c1[jb], wgB[13+ak], fmaf(c0[jb], wgB[ak], acc[jb][ak]));
    }

    // ---- pass B per b where needed: row (hk, mi0+1). FULLY UNROLLED so acc
    // indexing stays static (dynamic indexing demotes acc to scratch — R13 bug).
#pragma unroll
    for (int jb = 0; jb < 2; ++jb) {
        int rstar_j = rstar0 - 13*jb;
        if (rstar_j < 13) {
            int ustar = 60*rstar_j;
            int tstar = (ustar >= 1) ? (ustar/13) : -1;
            if (tk == tstar) {
#pragma unroll
                for (int j = 0; j < 13; ++j) myC[j] = acc[jb][j];
            }
            LDS_FENCE();
            if (tk >= tstar) {
#pragma unroll
                for (int j = 0; j < 13; ++j) acc[jb][j] = 0.f;
                const float* __restrict__ wrow2 = weff6 + (size_t)(hk*14 + mi0 + 1)*WROW6;
#pragma unroll 1
                for (int g = 0; g < 128; ++g) {
                    const float* wg = wrow2 + g*32;
                    float v0 = vX[jb*BSTRIDE + (2*g)*64];
                    float v1 = vX[jb*BSTRIDE + (2*g+1)*64];
#pragma unroll
                    for (int ak = 0; ak < 13; ++ak)
                        acc[jb][ak] = fmaf(v1, wg[13+ak], fmaf(v0, wg[ak], acc[jb][ak]));
                }
            }
            if (tk == tstar) {
#pragma unroll
                for (int j = 0; j < 13; ++j)
                    if (13*tk + j < ustar) acc[jb][j] = myC[j];
            }
            LDS_FENCE();
        }
    }

    // ---- softmax + AV per b; FULLY UNROLLED jb (static acc indexing)
    int dh = lane >> 2, cc = lane & 3;
#pragma unroll
    for (int jb = 0; jb < 2; ++jb) {
        int b = b0 + jb;
        int hb13 = (hk*1024 + b)*13;
        if (tk < NT) {
#pragma unroll
            for (int j = 0; j < 13; ++j) myC[13*tk + j] = acc[jb][j];
        }
        LDS_FENCE();
        float vreg[15];
#pragma unroll
        for (int j = 0; j < 15; ++j)
            vreg[j] = vgT[((size_t)b*NDM + hk*16 + dh)*64 + cc + 4*j];
#pragma unroll 1
        for (int r = 0; r < 13; ++r) {
            int n = hb13 + r;
            int m = n >> 10;                         // exact variant for this row
            int brow = (m*16 + hk)*13;
            float logit = -1e30f;
            if (lane < NT) {
                int u  = r*60 + lane;
                int ak = u % 13;
                logit = (myC[u] + beff2[brow + ak]) * 0.5f;
            }
            float mx = logit;
#pragma unroll
            for (int off = 32; off; off >>= 1) mx = fmaxf(mx, __shfl_xor(mx, off));
            float e = (lane < NT) ? __expf(logit - mx) : 0.f;
            float s = e;
#pragma unroll
            for (int off = 32; off; off >>= 1) s += __shfl_xor(s, off);
            float attn = e / s;
            if (lane < NT) myC[r*60 + lane] = attn;  // same-wave in-order LDS
            LDS_FENCE();
            float a = 0.f;
#pragma unroll
            for (int j = 0; j < 15; ++j)
                a = fmaf(myC[r*60 + cc + 4*j], vreg[j], a);
            a += __shfl_xor(a, 1);
            a += __shfl_xor(a, 2);
            if (cc == 0) attout[(size_t)n*NDH + dh] = a;
        }
        LDS_FENCE();
    }
}

// ---------------- K3: MLP + BN(eval) + ReLU + GroupNorm(16,128); 16 rows/block.
// R9-verified WIN (~75us): j = tid>>3, sl = tid&7 -> 8 lanes SHARE each W1
// row (float4 wave-load = 2 cachelines, was 64). f stride 260 keeps the 8
// distinct f[sl] reads conflict-free. GN octet at lane stride 8 -> shuffle
// offsets {8,16,32}. Math identical to original.
#define FS 260
__launch_bounds__(1024)
__global__ void ltae_mlp(const float* __restrict__ attout, const float* __restrict__ W1,
                         const float* __restrict__ b1, const float* __restrict__ bnw,
                         const float* __restrict__ bnb, const float* __restrict__ bnrm,
                         const float* __restrict__ bnrv, const float* __restrict__ gow,
                         const float* __restrict__ gob, float* __restrict__ out) {
    __shared__ float f[16*FS];   // 16,640 B
    int tid = threadIdx.x;
    int sl  = tid & 7;           // sample slot 0..7 (8 lanes share a W1 row)
    int j   = tid >> 3;          // output channel 0..127
    int base = blockIdx.x << 4;  // 16 sids per block; sid = a2*1024 + b2
    for (int k = tid; k < 16*NDM; k += 1024) {
        int s = k >> 8, c = k & 255;
        int sid2 = base + s;
        int aa = sid2 >> 10, bb = sid2 & 1023;
        int h2 = c >> 4, dhh = c & 15;
        f[s*FS + c] = attout[((size_t)((aa*16 + h2)*1024 + bb))*NDH + dhh];
    }
    __syncthreads();
    const float* fr0 = f + sl*FS;
    const float* fr1 = f + (sl+8)*FS;
    const float* w   = &W1[(size_t)j*NDM];
    float bj = b1[j];
    float acc0 = bj, acc1 = bj;
    for (int c = 0; c < NDM; c += 4) {
        float4 wv = *(const float4*)&w[c];      // 8 lanes/addr -> 2 lines/wave
        float4 f0 = *(const float4*)&fr0[c];    // 16B-aligned (FS*4 % 16 == 0)
        float4 f1 = *(const float4*)&fr1[c];
        acc0 += wv.x*f0.x + wv.y*f0.y + wv.z*f0.z + wv.w*f0.w;
        acc1 += wv.x*f1.x + wv.y*f1.y + wv.z*f1.z + wv.w*f1.w;
    }
    float rs = rsqrtf(bnrv[j] + 1e-5f);
    float sc = rs * bnw[j];
    float sh = bnb[j] - bnrm[j]*sc;
    float y0 = fmaxf(acc0*sc + sh, 0.f);
    float y1 = fmaxf(acc1*sc + sh, 0.f);
    float a1 = y0, b1s = y0*y0, a2 = y1, b2s = y1*y1;
#pragma unroll
    for (int off = 8; off < 64; off <<= 1) {    // GN octet at lane stride 8
        a1  += __shfl_xor(a1, off);
        b1s += __shfl_xor(b1s, off);
        a2  += __shfl_xor(a2, off);
        b2s += __shfl_xor(b2s, off);
    }
    float gw = gow[j], gb = gob[j];
    {
        float mean = a1 * 0.125f;
        float var  = b1s * 0.125f - mean*mean;
        float o = (y0 - mean) * rsqrtf(var + 1e-5f) * gw + gb;
        int sid = base + sl, aa = sid >> 10, bb = sid & 1023;
        out[((size_t)bb*NA + aa)*NMO + j] = o;
    }
    {
        float mean = a2 * 0.125f;
        float var  = b2s * 0.125f - mean*mean;
        float o = (y1 - mean) * rsqrtf(var + 1e-5f) * gw + gb;
        int sid = base + sl + 8, aa = sid >> 10, bb = sid & 1023;
        out[((size_t)bb*NA + aa)*NMO + j] = o;
    }
}

extern "C" void kernel_launch(void* const* d_in, const int* in_sizes, int n_in,
                              void* d_out, int out_size, void* d_ws, size_t ws_size,
                              hipStream_t stream) {
    const float* x    = (const float*)d_in[0];
    const float* Wc   = (const float*)d_in[1];
    const float* bc   = (const float*)d_in[2];
    const float* gnw  = (const float*)d_in[3];
    const float* gnb  = (const float*)d_in[4];
    const float* Q    = (const float*)d_in[5];
    const float* Wk   = (const float*)d_in[6];
    const float* bk   = (const float*)d_in[7];
    const float* W1   = (const float*)d_in[8];
    const float* b1   = (const float*)d_in[9];
    const float* bnw  = (const float*)d_in[10];
    const float* bnb  = (const float*)d_in[11];
    const float* bnrm = (const float*)d_in[12];
    const float* bnrv = (const float*)d_in[13];
    const float* gow  = (const float*)d_in[14];
    const float* gob  = (const float*)d_in[15];

    float* ws     = (float*)d_ws;
    float* weff6  = ws + OFF_WEFF;
    float* beff2  = ws + OFF_BEFF;
    float* vgT    = ws + OFF_VGT;
    float* attout = ws + OFF_ATT;
    float* outp   = (float*)d_out;

    hipLaunchKernelGGL(ltae_weff, dim3(NH*14), dim3(256), 0, stream, Q, Wk, bk, weff6, beff2);
    hipFuncSetAttribute((const void*)ltae_convgn,
                        hipFuncAttributeMaxDynamicSharedMemorySize, K1_LDS_BYTES);
    hipLaunchKernelGGL(ltae_convgn, dim3(NB), dim3(1024), K1_LDS_BYTES, stream,
                       x, Wc, bc, gnw, gnb, vgT);
    hipLaunchKernelGGL(ltae_attn, dim3(2048), dim3(256), 0, stream,
                       vgT, weff6, beff2, attout);
    hipLaunchKernelGGL(ltae_mlp, dim3(NA*NB/16), dim3(1024), 0, stream,
                       attout, W1, b1, bnw, bnb, bnrm, bnrv, gow, gob, outp);
}

// Round 12
// 322.078 us; speedup vs baseline: 1.5577x; 1.0210x over previous
//
#include <hip/hip_runtime.h>
#include <hip/hip_bf16.h>
#include <math.h>

// Problem constants
#define NB   1024   // batch
#define NT   60     // time steps
#define NC   10     // in channels
#define NDM  256    // d_model
#define NH   16     // heads
#define NDH  16     // per-head value dim
#define NA   13     // num attention queries
#define NM   208    // NA*NH
#define NMO  128    // MLP out

// weff6 row: 128 groups x 32 floats (128 B aligned); group g = d-pair (2g, 2g+1),
// slot dl*13+ak for dl in {0,1}; slots 26..31 pad. Row = 4096 floats.
#define WROW6 4096

// Workspace layout (floats)
#define OFF_WEFF  0
#define N_WEFF    (NH*14*WROW6)                // 917,504
#define OFF_BEFF  (OFF_WEFF + N_WEFF)
#define N_BEFF    (NM*NH*NA)                   // 43,264
#define OFF_VGT   (OFF_BEFF + N_BEFF)
#define N_VGT     (NB*NDM*64)                  // 16,777,216 (v transposed [b][d][64])
#define OFF_ATT   (OFF_VGT + N_VGT)
#define N_ATT     (NM*NB*NDH)                  // 3,407,872

#define LDS_FENCE() __asm__ __volatile__("s_waitcnt lgkmcnt(0)" ::: "memory")

// ---------------- K0: weff6[hk][mi][g][32], m = 13*hk+mi
__global__ void ltae_weff(const float* __restrict__ Q, const float* __restrict__ Wk,
                          const float* __restrict__ bk, float* __restrict__ weff6,
                          float* __restrict__ beff2) {
    int blk = blockIdx.x;            // hk*14 + mi
    int hk = blk / 14, mi = blk - hk*14;
    int m  = hk*13 + mi;
    int mc = m > 207 ? 207 : m;      // slot (15,13) provably never read
    int d = threadIdx.x;
    float q0 = Q[mc*4+0], q1 = Q[mc*4+1], q2 = Q[mc*4+2], q3 = Q[mc*4+3];
    int g = d >> 1, dl = d & 1;
    size_t base = (size_t)blk*WROW6 + g*32 + dl*13;
#pragma unroll
    for (int ak = 0; ak < NA; ++ak) {
        int e = (ak*16 + hk)*4;
        float w = q0*Wk[(size_t)(e+0)*NDM + d] + q1*Wk[(size_t)(e+1)*NDM + d]
                + q2*Wk[(size_t)(e+2)*NDM + d] + q3*Wk[(size_t)(e+3)*NDM + d];
        weff6[base + ak] = w;
    }
    if (dl == 1) {               // zero the 6 pad slots of this group
#pragma unroll
        for (int p = 26; p < 32; ++p) weff6[(size_t)blk*WROW6 + g*32 + p] = 0.f;
    }
    if (d < NA && m <= 207) {
        int e = (d*16 + hk)*4;
        beff2[(m*16 + hk)*NA + d] = q0*bk[e] + q1*bk[e+1] + q2*bk[e+2] + q3*bk[e+3];
    }
}

// ---------------- K1: conv 1x1 + GroupNorm -> vgT[b][d][64] (t-padded, coalesced)
#define VT_S 66
#define K1_LDS_BYTES ((NDM*VT_S + NT*NC)*4)

__launch_bounds__(1024, 8)
__global__ void ltae_convgn(const float* __restrict__ x, const float* __restrict__ Wc,
                            const float* __restrict__ bc, const float* __restrict__ gnw,
                            const float* __restrict__ gnb, float* __restrict__ vgT) {
    extern __shared__ float smem[];
    float* Vt = smem;
    float* xs = smem + NDM*VT_S;
    int b = blockIdx.x, tid = threadIdx.x;
    if (tid < NT*NC) xs[tid] = x[(size_t)b*NT*NC + tid];
    __syncthreads();
    {
        int d = tid >> 2, q = tid & 3;   // wave = 16 d = one GN group
        float wc[NC];
#pragma unroll
        for (int c = 0; c < NC; ++c) wc[c] = Wc[d*NC + c];
        float bcv = bc[d];
        float h[15];
        float s1 = 0.f, s2 = 0.f;
#pragma unroll
        for (int k = 0; k < 15; ++k) {
            int t = 15*q + k;
            float a = bcv;
#pragma unroll
            for (int c = 0; c < NC; ++c) a = fmaf(xs[t*NC + c], wc[c], a);
            h[k] = a; s1 += a; s2 += a*a;
        }
#pragma unroll
        for (int off = 1; off < 64; off <<= 1) {
            s1 += __shfl_xor(s1, off);
            s2 += __shfl_xor(s2, off);
        }
        float mean = s1 * (1.f/960.f);
        float var  = s2 * (1.f/960.f) - mean*mean;
        float rstd = rsqrtf(var + 1e-5f);
        float g = gnw[d], bb = gnb[d];
#pragma unroll
        for (int k = 0; k < 15; ++k)
            Vt[d*VT_S + 15*q + k] = (h[k]-mean)*rstd*g + bb;
    }
    __syncthreads();
    // float4 stores: 4x fewer store instructions than scalar
    float* vb = vgT + (size_t)b*NDM*64;
    for (int i = tid; i < NDM*16; i += 1024) {
        int d = i >> 4, t4 = (i & 15) << 2;
        float4 o;
        o.x = (t4+0 < NT) ? Vt[d*VT_S + t4+0] : 0.f;
        o.y = (t4+1 < NT) ? Vt[d*VT_S + t4+1] : 0.f;
        o.z = (t4+2 < NT) ? Vt[d*VT_S + t4+2] : 0.f;
        o.w = (t4+3 < NT) ? Vt[d*VT_S + t4+3] : 0.f;
        *(float4*)&vb[d*64 + t4] = o;
    }
}

// ---------------- K2: scrambled attention; 128-THREAD BLOCKS (2 waves).
// R11 falsified the scalar-weight theory (weight-sharing mapping: neutral).
// Eleven structures pin at VALUBusy 43% / ~192us; the only lever that ever
// moved achieved residency is BLOCK SIZE: 256-thr gangs plateau at 40% occ,
// R7's 128-thr gangs hit 55% (and the lowest VALU-busy-time). R7 lost only
// to its doubled weight stream — so R12 isolates the one variable: R11's
// per-wave code byte-identical, gang halved to 2 waves (1 hk x 2 b-pairs).
// Grid 4096 = 8 xcd * 32 bg4 * 16 hk; all 16 hk of one b-quad on one XCD
// (same 8MB/XCD v footprint as R11). launch_bounds(128,8): VGPR cap 64>>28,
// LDS 6272B -> 16 wg/CU fits (100KB).
#define BSTRIDE (NDM*64)
__launch_bounds__(128, 8)
__global__ void ltae_attn(const float* __restrict__ vgT, const float* __restrict__ weff6,
                          const float* __restrict__ beff2, float* __restrict__ attout) {
    __shared__ float wbuf[2*784];        // 6,272 B
    int p = blockIdx.x;                  // 4096 = 8 xcd * 32 bg4 * 16 hk
    int xcd = p & 7, idx = p >> 3;
    int bg4 = xcd * 32 + (idx >> 4);     // bijective: 8*32*16 = 4096
    int hkq = idx & 15;                  // block's head index
    int tid = threadIdx.x;
    int wid = tid >> 6, lane = tid & 63;
    int hk = __builtin_amdgcn_readfirstlane(hkq);        // uniform -> scalar path
    int b0 = __builtin_amdgcn_readfirstlane(bg4*4 + wid*2);  // scalar b0 (R10 lesson)
    int tk = lane;
    int mi0    = (13*b0) >> 10;                          // provably scalar
    int rstar0 = ((mi0+1) << 10) - 13*b0;                // switch for b0+jb iff rstar0-13jb < 13
    const float* __restrict__ wrow = weff6 + (size_t)(hk*14 + mi0)*WROW6;
    const float* __restrict__ vX   = vgT + (size_t)b0*BSTRIDE + tk;
    float* myC = wbuf + wid*784;

    float acc[2][13];
#pragma unroll
    for (int jb = 0; jb < 2; ++jb)
#pragma unroll
        for (int j = 0; j < 13; ++j) acc[jb][j] = 0.f;

    // ---- pass A: row (hk, mi0), 128 d-pair groups (2 per iteration), shared
    // across 2 b. Loads batched up-front, FMAs after a single wait pair.
#pragma unroll 1
    for (int gg = 0; gg < 64; ++gg) {
        const float* wgA = wrow + (size_t)(2*gg)*32;     // uniform -> s_load
        const float* wgB = wrow + (size_t)(2*gg+1)*32;
        float a0[2], a1[2], c0[2], c1[2];
#pragma unroll
        for (int jb = 0; jb < 2; ++jb) {
            a0[jb] = vX[jb*BSTRIDE + (4*gg+0)*64];
            a1[jb] = vX[jb*BSTRIDE + (4*gg+1)*64];
            c0[jb] = vX[jb*BSTRIDE + (4*gg+2)*64];
            c1[jb] = vX[jb*BSTRIDE + (4*gg+3)*64];
        }
#pragma unroll
        for (int jb = 0; jb < 2; ++jb)
#pragma unroll
            for (int ak = 0; ak < 13; ++ak)
                acc[jb][ak] = fmaf(a1[jb], wgA[13+ak], fmaf(a0[jb], wgA[ak], acc[jb][ak]));
#pragma unroll
        for (int jb = 0; jb < 2; ++jb)
#pragma unroll
            for (int ak = 0; ak < 13; ++ak)
                acc[jb][ak] = fmaf(c1[jb], wgB[13+ak], fmaf(c0[jb], wgB[ak], acc[jb][ak]));
    }

    // ---- pass B per b where needed: row (hk, mi0+1). FULLY UNROLLED so acc
    // indexing stays static (dynamic indexing demotes acc to scratch — R13 bug).
#pragma unroll
    for (int jb = 0; jb < 2; ++jb) {
        int rstar_j = rstar0 - 13*jb;
        if (rstar_j < 13) {
            int ustar = 60*rstar_j;
            int tstar = (ustar >= 1) ? (ustar/13) : -1;
            if (tk == tstar) {
#pragma unroll
                for (int j = 0; j < 13; ++j) myC[j] = acc[jb][j];
            }
            LDS_FENCE();
            if (tk >= tstar) {
#pragma unroll
                for (int j = 0; j < 13; ++j) acc[jb][j] = 0.f;
                const float* __restrict__ wrow2 = weff6 + (size_t)(hk*14 + mi0 + 1)*WROW6;
#pragma unroll 1
                for (int g = 0; g < 128; ++g) {
                    const float* wg = wrow2 + g*32;
                    float v0 = vX[jb*BSTRIDE + (2*g)*64];
                    float v1 = vX[jb*BSTRIDE + (2*g+1)*64];
#pragma unroll
                    for (int ak = 0; ak < 13; ++ak)
                        acc[jb][ak] = fmaf(v1, wg[13+ak], fmaf(v0, wg[ak], acc[jb][ak]));
                }
            }
            if (tk == tstar) {
#pragma unroll
                for (int j = 0; j < 13; ++j)
                    if (13*tk + j < ustar) acc[jb][j] = myC[j];
            }
            LDS_FENCE();
        }
    }

    // ---- softmax + AV per b; FULLY UNROLLED jb (static acc indexing)
    int dh = lane >> 2, cc = lane & 3;
#pragma unroll
    for (int jb = 0; jb < 2; ++jb) {
        int b = b0 + jb;
        int hb13 = (hk*1024 + b)*13;
        if (tk < NT) {
#pragma unroll
            for (int j = 0; j < 13; ++j) myC[13*tk + j] = acc[jb][j];
        }
        LDS_FENCE();
        float vreg[15];
#pragma unroll
        for (int j = 0; j < 15; ++j)
            vreg[j] = vgT[((size_t)b*NDM + hk*16 + dh)*64 + cc + 4*j];
#pragma unroll 1
        for (int r = 0; r < 13; ++r) {
            int n = hb13 + r;
            int m = n >> 10;                         // exact variant for this row
            int brow = (m*16 + hk)*13;
            float logit = -1e30f;
            if (lane < NT) {
                int u  = r*60 + lane;
                int ak = u % 13;
                logit = (myC[u] + beff2[brow + ak]) * 0.5f;
            }
            float mx = logit;
#pragma unroll
            for (int off = 32; off; off >>= 1) mx = fmaxf(mx, __shfl_xor(mx, off));
            float e = (lane < NT) ? __expf(logit - mx) : 0.f;
            float s = e;
#pragma unroll
            for (int off = 32; off; off >>= 1) s += __shfl_xor(s, off);
            float attn = e / s;
            if (lane < NT) myC[r*60 + lane] = attn;  // same-wave in-order LDS
            LDS_FENCE();
            float a = 0.f;
#pragma unroll
            for (int j = 0; j < 15; ++j)
                a = fmaf(myC[r*60 + cc + 4*j], vreg[j], a);
            a += __shfl_xor(a, 1);
            a += __shfl_xor(a, 2);
            if (cc == 0) attout[(size_t)n*NDH + dh] = a;
        }
        LDS_FENCE();
    }
}

// ---------------- K3: MLP + BN(eval) + ReLU + GroupNorm(16,128); 16 rows/block.
// R9-verified WIN (~75us): j = tid>>3, sl = tid&7 -> 8 lanes SHARE each W1
// row (float4 wave-load = 2 cachelines, was 64). f stride 260 keeps the 8
// distinct f[sl] reads conflict-free. GN octet at lane stride 8 -> shuffle
// offsets {8,16,32}. Math identical to original.
#define FS 260
__launch_bounds__(1024)
__global__ void ltae_mlp(const float* __restrict__ attout, const float* __restrict__ W1,
                         const float* __restrict__ b1, const float* __restrict__ bnw,
                         const float* __restrict__ bnb, const float* __restrict__ bnrm,
                         const float* __restrict__ bnrv, const float* __restrict__ gow,
                         const float* __restrict__ gob, float* __restrict__ out) {
    __shared__ float f[16*FS];   // 16,640 B
    int tid = threadIdx.x;
    int sl  = tid & 7;           // sample slot 0..7 (8 lanes share a W1 row)
    int j   = tid >> 3;          // output channel 0..127
    int base = blockIdx.x << 4;  // 16 sids per block; sid = a2*1024 + b2
    for (int k = tid; k < 16*NDM; k += 1024) {
        int s = k >> 8, c = k & 255;
        int sid2 = base + s;
        int aa = sid2 >> 10, bb = sid2 & 1023;
        int h2 = c >> 4, dhh = c & 15;
        f[s*FS + c] = attout[((size_t)((aa*16 + h2)*1024 + bb))*NDH + dhh];
    }
    __syncthreads();
    const float* fr0 = f + sl*FS;
    const float* fr1 = f + (sl+8)*FS;
    const float* w   = &W1[(size_t)j*NDM];
    float bj = b1[j];
    float acc0 = bj, acc1 = bj;
    for (int c = 0; c < NDM; c += 4) {
        float4 wv = *(const float4*)&w[c];      // 8 lanes/addr -> 2 lines/wave
        float4 f0 = *(const float4*)&fr0[c];    // 16B-aligned (FS*4 % 16 == 0)
        float4 f1 = *(const float4*)&fr1[c];
        acc0 += wv.x*f0.x + wv.y*f0.y + wv.z*f0.z + wv.w*f0.w;
        acc1 += wv.x*f1.x + wv.y*f1.y + wv.z*f1.z + wv.w*f1.w;
    }
    float rs = rsqrtf(bnrv[j] + 1e-5f);
    float sc = rs * bnw[j];
    float sh = bnb[j] - bnrm[j]*sc;
    float y0 = fmaxf(acc0*sc + sh, 0.f);
    float y1 = fmaxf(acc1*sc + sh, 0.f);
    float a1 = y0, b1s = y0*y0, a2 = y1, b2s = y1*y1;
#pragma unroll
    for (int off = 8; off < 64; off <<= 1) {    // GN octet at lane stride 8
        a1  += __shfl_xor(a1, off);
        b1s += __shfl_xor(b1s, off);
        a2  += __shfl_xor(a2, off);
        b2s += __shfl_xor(b2s, off);
    }
    float gw = gow[j], gb = gob[j];
    {
        float mean = a1 * 0.125f;
        float var  = b1s * 0.125f - mean*mean;
        float o = (y0 - mean) * rsqrtf(var + 1e-5f) * gw + gb;
        int sid = base + sl, aa = sid >> 10, bb = sid & 1023;
        out[((size_t)bb*NA + aa)*NMO + j] = o;
    }
    {
        float mean = a2 * 0.125f;
        float var  = b2s * 0.125f - mean*mean;
        float o = (y1 - mean) * rsqrtf(var + 1e-5f) * gw + gb;
        int sid = base + sl + 8, aa = sid >> 10, bb = sid & 1023;
        out[((size_t)bb*NA + aa)*NMO + j] = o;
    }
}

extern "C" void kernel_launch(void* const* d_in, const int* in_sizes, int n_in,
                              void* d_out, int out_size, void* d_ws, size_t ws_size,
                              hipStream_t stream) {
    const float* x    = (const float*)d_in[0];
    const float* Wc   = (const float*)d_in[1];
    const float* bc   = (const float*)d_in[2];
    const float* gnw  = (const float*)d_in[3];
    const float* gnb  = (const float*)d_in[4];
    const float* Q    = (const float*)d_in[5];
    const float* Wk   = (const float*)d_in[6];
    const float* bk   = (const float*)d_in[7];
    const float* W1   = (const float*)d_in[8];
    const float* b1   = (const float*)d_in[9];
    const float* bnw  = (const float*)d_in[10];
    const float* bnb  = (const float*)d_in[11];
    const float* bnrm = (const float*)d_in[12];
    const float* bnrv = (const float*)d_in[13];
    const float* gow  = (const float*)d_in[14];
    const float* gob  = (const float*)d_in[15];

    float* ws     = (float*)d_ws;
    float* weff6  = ws + OFF_WEFF;
    float* beff2  = ws + OFF_BEFF;
    float* vgT    = ws + OFF_VGT;
    float* attout = ws + OFF_ATT;
    float* outp   = (float*)d_out;

    hipLaunchKernelGGL(ltae_weff, dim3(NH*14), dim3(256), 0, stream, Q, Wk, bk, weff6, beff2);
    hipFuncSetAttribute((const void*)ltae_convgn,
                        hipFuncAttributeMaxDynamicSharedMemorySize, K1_LDS_BYTES);
    hipLaunchKernelGGL(ltae_convgn, dim3(NB), dim3(1024), K1_LDS_BYTES, stream,
                       x, Wc, bc, gnw, gnb, vgT);
    hipLaunchKernelGGL(ltae_attn, dim3(4096), dim3(128), 0, stream,
                       vgT, weff6, beff2, attout);
    hipLaunchKernelGGL(ltae_mlp, dim3(NA*NB/16), dim3(1024), 0, stream,
                       attout, W1, b1, bnw, bnb, bnrm, bnrv, gow, gob, outp);
}

// Round 13
// 292.680 us; speedup vs baseline: 1.7142x; 1.1004x over previous
//
#include <hip/hip_runtime.h>
#include <hip/hip_bf16.h>
#include <math.h>

// Problem constants
#define NB   1024   // batch
#define NT   60     // time steps
#define NC   10     // in channels
#define NDM  256    // d_model
#define NH   16     // heads
#define NDH  16     // per-head value dim
#define NA   13     // num attention queries
#define NM   208    // NA*NH
#define NMO  128    // MLP out

// weff6 row: 128 groups x 32 floats (128 B aligned); group g = d-pair (2g, 2g+1),
// slot dl*13+ak for dl in {0,1}; slots 26..31 pad. Row = 4096 floats.
#define WROW6 4096

// Workspace layout (floats)
#define OFF_WEFF  0
#define N_WEFF    (NH*14*WROW6)                // 917,504
#define OFF_BEFF  (OFF_WEFF + N_WEFF)
#define N_BEFF    (NM*NH*NA)                   // 43,264
#define OFF_VGT   (OFF_BEFF + N_BEFF)
#define N_VGT     (NB*NDM*64)                  // 16,777,216 (v transposed [b][d][64])
#define OFF_ATT   (OFF_VGT + N_VGT)
#define N_ATT     (NM*NB*NDH)                  // 3,407,872

#define LDS_FENCE() __asm__ __volatile__("s_waitcnt lgkmcnt(0)" ::: "memory")

// ---------------- K0: weff6[hk][mi][g][32], m = 13*hk+mi
__global__ void ltae_weff(const float* __restrict__ Q, const float* __restrict__ Wk,
                          const float* __restrict__ bk, float* __restrict__ weff6,
                          float* __restrict__ beff2) {
    int blk = blockIdx.x;            // hk*14 + mi
    int hk = blk / 14, mi = blk - hk*14;
    int m  = hk*13 + mi;
    int mc = m > 207 ? 207 : m;      // slot (15,13) provably never read
    int d = threadIdx.x;
    float q0 = Q[mc*4+0], q1 = Q[mc*4+1], q2 = Q[mc*4+2], q3 = Q[mc*4+3];
    int g = d >> 1, dl = d & 1;
    size_t base = (size_t)blk*WROW6 + g*32 + dl*13;
#pragma unroll
    for (int ak = 0; ak < NA; ++ak) {
        int e = (ak*16 + hk)*4;
        float w = q0*Wk[(size_t)(e+0)*NDM + d] + q1*Wk[(size_t)(e+1)*NDM + d]
                + q2*Wk[(size_t)(e+2)*NDM + d] + q3*Wk[(size_t)(e+3)*NDM + d];
        weff6[base + ak] = w;
    }
    if (dl == 1) {               // zero the 6 pad slots of this group
#pragma unroll
        for (int p = 26; p < 32; ++p) weff6[(size_t)blk*WROW6 + g*32 + p] = 0.f;
    }
    if (d < NA && m <= 207) {
        int e = (d*16 + hk)*4;
        beff2[(m*16 + hk)*NA + d] = q0*bk[e] + q1*bk[e+1] + q2*bk[e+2] + q3*bk[e+3];
    }
}

// ---------------- K1: conv 1x1 + GroupNorm -> vgT[b][d][64] (t-padded, coalesced)
#define VT_S 66
#define K1_LDS_BYTES ((NDM*VT_S + NT*NC)*4)

__launch_bounds__(1024, 8)
__global__ void ltae_convgn(const float* __restrict__ x, const float* __restrict__ Wc,
                            const float* __restrict__ bc, const float* __restrict__ gnw,
                            const float* __restrict__ gnb, float* __restrict__ vgT) {
    extern __shared__ float smem[];
    float* Vt = smem;
    float* xs = smem + NDM*VT_S;
    int b = blockIdx.x, tid = threadIdx.x;
    if (tid < NT*NC) xs[tid] = x[(size_t)b*NT*NC + tid];
    __syncthreads();
    {
        int d = tid >> 2, q = tid & 3;   // wave = 16 d = one GN group
        float wc[NC];
#pragma unroll
        for (int c = 0; c < NC; ++c) wc[c] = Wc[d*NC + c];
        float bcv = bc[d];
        float h[15];
        float s1 = 0.f, s2 = 0.f;
#pragma unroll
        for (int k = 0; k < 15; ++k) {
            int t = 15*q + k;
            float a = bcv;
#pragma unroll
            for (int c = 0; c < NC; ++c) a = fmaf(xs[t*NC + c], wc[c], a);
            h[k] = a; s1 += a; s2 += a*a;
        }
#pragma unroll
        for (int off = 1; off < 64; off <<= 1) {
            s1 += __shfl_xor(s1, off);
            s2 += __shfl_xor(s2, off);
        }
        float mean = s1 * (1.f/960.f);
        float var  = s2 * (1.f/960.f) - mean*mean;
        float rstd = rsqrtf(var + 1e-5f);
        float g = gnw[d], bb = gnb[d];
#pragma unroll
        for (int k = 0; k < 15; ++k)
            Vt[d*VT_S + 15*q + k] = (h[k]-mean)*rstd*g + bb;
    }
    __syncthreads();
    // float4 stores: 4x fewer store instructions than scalar
    float* vb = vgT + (size_t)b*NDM*64;
    for (int i = tid; i < NDM*16; i += 1024) {
        int d = i >> 4, t4 = (i & 15) << 2;
        float4 o;
        o.x = (t4+0 < NT) ? Vt[d*VT_S + t4+0] : 0.f;
        o.y = (t4+1 < NT) ? Vt[d*VT_S + t4+1] : 0.f;
        o.z = (t4+2 < NT) ? Vt[d*VT_S + t4+2] : 0.f;
        o.w = (t4+3 < NT) ? Vt[d*VT_S + t4+3] : 0.f;
        *(float4*)&vb[d*64 + t4] = o;
    }
}

// ---------------- K2: scrambled attention; JB=1 — one (b,hk) pair per wave.
// R12 post-mortem: every prior config had <= 16 blocks/CU of WORK = one
// residency generation (~15 waves/CU, 3.7/SIMD) because grid/256 never
// exceeded the 16-wg/CU cap. JB=1 doubles the wave count: 8192 blocks =
// 32 blocks/CU of work; 16 wg x 2 waves = 32 waves/CU RESIDENT (2 gens).
// Per-wave code is the proven R2/R12 structure with half the state
// (acc[13], ~24 VGPR). Total v volume unchanged (64 KB per (b,hk) either
// way); weight reads double but ride the scalar/L2 path R11 proved
// non-binding. Block = (1 b x 2 hk): the 2 waves time-share one v panel.
// Epilogue halves per wave (13 rows).
#define BSTRIDE (NDM*64)
__launch_bounds__(128, 8)
__global__ void ltae_attn(const float* __restrict__ vgT, const float* __restrict__ weff6,
                          const float* __restrict__ beff2, float* __restrict__ attout) {
    __shared__ float wbuf[2*784];        // 6,272 B
    int p = blockIdx.x;                  // 8192 = 8 xcd * 128 b * 8 hkp
    int xcd = p & 7, idx = p >> 3;
    int b   = xcd * 128 + (idx >> 3);    // bijective: 8*128*8 = 8192
    int hkp = idx & 7;                   // block's hk pair
    int tid = threadIdx.x;
    int wid = tid >> 6, lane = tid & 63;
    int hk = __builtin_amdgcn_readfirstlane(hkp*2 + wid);  // wave-uniform scalar
    int tk = lane;
    int mi0   = (13*b) >> 10;                            // block-uniform scalar
    int rstar = ((mi0+1) << 10) - 13*b;                  // pass B iff rstar < 13
    const float* __restrict__ wrow = weff6 + (size_t)(hk*14 + mi0)*WROW6;
    const float* __restrict__ vX   = vgT + (size_t)b*BSTRIDE + tk;
    float* myC = wbuf + wid*784;

    float acc[13];
#pragma unroll
    for (int j = 0; j < 13; ++j) acc[j] = 0.f;

    // ---- pass A: row (hk, mi0), 128 d-pair groups (2 per iteration).
    // 4 v loads batched up-front, 52 FMAs after a single wait pair.
#pragma unroll 1
    for (int gg = 0; gg < 64; ++gg) {
        const float* wgA = wrow + (size_t)(2*gg)*32;     // uniform -> s_load
        const float* wgB = wrow + (size_t)(2*gg+1)*32;
        float a0 = vX[(4*gg+0)*64];
        float a1 = vX[(4*gg+1)*64];
        float c0 = vX[(4*gg+2)*64];
        float c1 = vX[(4*gg+3)*64];
#pragma unroll
        for (int ak = 0; ak < 13; ++ak)
            acc[ak] = fmaf(a1, wgA[13+ak], fmaf(a0, wgA[ak], acc[ak]));
#pragma unroll
        for (int ak = 0; ak < 13; ++ak)
            acc[ak] = fmaf(c1, wgB[13+ak], fmaf(c0, wgB[ak], acc[ak]));
    }

    // ---- pass B (rare): rows r >= rstar use weight row mi0+1.
    if (rstar < 13) {
        int ustar = 60*rstar;
        int tstar = (ustar >= 1) ? (ustar/13) : -1;
        if (tk == tstar) {
#pragma unroll
            for (int j = 0; j < 13; ++j) myC[j] = acc[j];
        }
        LDS_FENCE();
        if (tk >= tstar) {
#pragma unroll
            for (int j = 0; j < 13; ++j) acc[j] = 0.f;
            const float* __restrict__ wrow2 = weff6 + (size_t)(hk*14 + mi0 + 1)*WROW6;
#pragma unroll 1
            for (int g = 0; g < 128; ++g) {
                const float* wg = wrow2 + g*32;
                float v0 = vX[(2*g)*64];
                float v1 = vX[(2*g+1)*64];
#pragma unroll
                for (int ak = 0; ak < 13; ++ak)
                    acc[ak] = fmaf(v1, wg[13+ak], fmaf(v0, wg[ak], acc[ak]));
            }
        }
        if (tk == tstar) {
#pragma unroll
            for (int j = 0; j < 13; ++j)
                if (13*tk + j < ustar) acc[j] = myC[j];
        }
        LDS_FENCE();
    }

    // ---- softmax + AV (single b, single hk); exact R2 row structure.
    int dh = lane >> 2, cc = lane & 3;
    int hb13 = (hk*1024 + b)*13;
    if (tk < NT) {
#pragma unroll
        for (int j = 0; j < 13; ++j) myC[13*tk + j] = acc[j];
    }
    LDS_FENCE();
    float vreg[15];
#pragma unroll
    for (int j = 0; j < 15; ++j)
        vreg[j] = vgT[((size_t)b*NDM + hk*16 + dh)*64 + cc + 4*j];
#pragma unroll 1
    for (int r = 0; r < 13; ++r) {
        int n = hb13 + r;
        int m = n >> 10;                         // exact variant for this row
        int brow = (m*16 + hk)*13;
        float logit = -1e30f;
        if (lane < NT) {
            int u  = r*60 + lane;
            int ak = u % 13;
            logit = (myC[u] + beff2[brow + ak]) * 0.5f;
        }
        float mx = logit;
#pragma unroll
        for (int off = 32; off; off >>= 1) mx = fmaxf(mx, __shfl_xor(mx, off));
        float e = (lane < NT) ? __expf(logit - mx) : 0.f;
        float s = e;
#pragma unroll
        for (int off = 32; off; off >>= 1) s += __shfl_xor(s, off);
        float attn = e / s;
        if (lane < NT) myC[r*60 + lane] = attn;  // same-wave in-order LDS
        LDS_FENCE();
        float a = 0.f;
#pragma unroll
        for (int j = 0; j < 15; ++j)
            a = fmaf(myC[r*60 + cc + 4*j], vreg[j], a);
        a += __shfl_xor(a, 1);
        a += __shfl_xor(a, 2);
        if (cc == 0) attout[(size_t)n*NDH + dh] = a;
    }
}

// ---------------- K3: MLP + BN(eval) + ReLU + GroupNorm(16,128); 16 rows/block.
// R9-verified WIN (~75us): j = tid>>3, sl = tid&7 -> 8 lanes SHARE each W1
// row (float4 wave-load = 2 cachelines, was 64). f stride 260 keeps the 8
// distinct f[sl] reads conflict-free. GN octet at lane stride 8 -> shuffle
// offsets {8,16,32}. Math identical to original.
#define FS 260
__launch_bounds__(1024)
__global__ void ltae_mlp(const float* __restrict__ attout, const float* __restrict__ W1,
                         const float* __restrict__ b1, const float* __restrict__ bnw,
                         const float* __restrict__ bnb, const float* __restrict__ bnrm,
                         const float* __restrict__ bnrv, const float* __restrict__ gow,
                         const float* __restrict__ gob, float* __restrict__ out) {
    __shared__ float f[16*FS];   // 16,640 B
    int tid = threadIdx.x;
    int sl  = tid & 7;           // sample slot 0..7 (8 lanes share a W1 row)
    int j   = tid >> 3;          // output channel 0..127
    int base = blockIdx.x << 4;  // 16 sids per block; sid = a2*1024 + b2
    for (int k = tid; k < 16*NDM; k += 1024) {
        int s = k >> 8, c = k & 255;
        int sid2 = base + s;
        int aa = sid2 >> 10, bb = sid2 & 1023;
        int h2 = c >> 4, dhh = c & 15;
        f[s*FS + c] = attout[((size_t)((aa*16 + h2)*1024 + bb))*NDH + dhh];
    }
    __syncthreads();
    const float* fr0 = f + sl*FS;
    const float* fr1 = f + (sl+8)*FS;
    const float* w   = &W1[(size_t)j*NDM];
    float bj = b1[j];
    float acc0 = bj, acc1 = bj;
    for (int c = 0; c < NDM; c += 4) {
        float4 wv = *(const float4*)&w[c];      // 8 lanes/addr -> 2 lines/wave
        float4 f0 = *(const float4*)&fr0[c];    // 16B-aligned (FS*4 % 16 == 0)
        float4 f1 = *(const float4*)&fr1[c];
        acc0 += wv.x*f0.x + wv.y*f0.y + wv.z*f0.z + wv.w*f0.w;
        acc1 += wv.x*f1.x + wv.y*f1.y + wv.z*f1.z + wv.w*f1.w;
    }
    float rs = rsqrtf(bnrv[j] + 1e-5f);
    float sc = rs * bnw[j];
    float sh = bnb[j] - bnrm[j]*sc;
    float y0 = fmaxf(acc0*sc + sh, 0.f);
    float y1 = fmaxf(acc1*sc + sh, 0.f);
    float a1 = y0, b1s = y0*y0, a2 = y1, b2s = y1*y1;
#pragma unroll
    for (int off = 8; off < 64; off <<= 1) {    // GN octet at lane stride 8
        a1  += __shfl_xor(a1, off);
        b1s += __shfl_xor(b1s, off);
        a2  += __shfl_xor(a2, off);
        b2s += __shfl_xor(b2s, off);
    }
    float gw = gow[j], gb = gob[j];
    {
        float mean = a1 * 0.125f;
        float var  = b1s * 0.125f - mean*mean;
        float o = (y0 - mean) * rsqrtf(var + 1e-5f) * gw + gb;
        int sid = base + sl, aa = sid >> 10, bb = sid & 1023;
        out[((size_t)bb*NA + aa)*NMO + j] = o;
    }
    {
        float mean = a2 * 0.125f;
        float var  = b2s * 0.125f - mean*mean;
        float o = (y1 - mean) * rsqrtf(var + 1e-5f) * gw + gb;
        int sid = base + sl + 8, aa = sid >> 10, bb = sid & 1023;
        out[((size_t)bb*NA + aa)*NMO + j] = o;
    }
}

extern "C" void kernel_launch(void* const* d_in, const int* in_sizes, int n_in,
                              void* d_out, int out_size, void* d_ws, size_t ws_size,
                              hipStream_t stream) {
    const float* x    = (const float*)d_in[0];
    const float* Wc   = (const float*)d_in[1];
    const float* bc   = (const float*)d_in[2];
    const float* gnw  = (const float*)d_in[3];
    const float* gnb  = (const float*)d_in[4];
    const float* Q    = (const float*)d_in[5];
    const float* Wk   = (const float*)d_in[6];
    const float* bk   = (const float*)d_in[7];
    const float* W1   = (const float*)d_in[8];
    const float* b1   = (const float*)d_in[9];
    const float* bnw  = (const float*)d_in[10];
    const float* bnb  = (const float*)d_in[11];
    const float* bnrm = (const float*)d_in[12];
    const float* bnrv = (const float*)d_in[13];
    const float* gow  = (const float*)d_in[14];
    const float* gob  = (const float*)d_in[15];

    float* ws     = (float*)d_ws;
    float* weff6  = ws + OFF_WEFF;
    float* beff2  = ws + OFF_BEFF;
    float* vgT    = ws + OFF_VGT;
    float* attout = ws + OFF_ATT;
    float* outp   = (float*)d_out;

    hipLaunchKernelGGL(ltae_weff, dim3(NH*14), dim3(256), 0, stream, Q, Wk, bk, weff6, beff2);
    hipFuncSetAttribute((const void*)ltae_convgn,
                        hipFuncAttributeMaxDynamicSharedMemorySize, K1_LDS_BYTES);
    hipLaunchKernelGGL(ltae_convgn, dim3(NB), dim3(1024), K1_LDS_BYTES, stream,
                       x, Wc, bc, gnw, gnb, vgT);
    hipLaunchKernelGGL(ltae_attn, dim3(8192), dim3(128), 0, stream,
                       vgT, weff6, beff2, attout);
    hipLaunchKernelGGL(ltae_mlp, dim3(NA*NB/16), dim3(1024), 0, stream,
                       attout, W1, b1, bnw, bnb, bnrm, bnrv, gow, gob, outp);
}